// Round 9
// baseline (1610.714 us; speedup 1.0000x reference)
//
#include <hip/hip_runtime.h>
#include <hip/hip_bf16.h>
#include <stdint.h>

// Problem constants (SNNExoplanetDetector): B=256 batch, T=1000 steps,
// F=128 input feats, H=256 hidden, O=2 outputs.
constexpr int B = 256, T = 1000, F = 128, H = 256, O = 2;
constexpr float DT_TAU_MEM = 0.1f;   // DT * TAU_MEM_INV
constexpr float SYN_DECAY  = 0.8f;   // 1 - DT * TAU_SYN_INV
constexpr float V_THRESH   = 1.0f;

typedef __attribute__((ext_vector_type(8))) _Float16 half8v;  // 8 f16 = 4 VGPR
typedef __attribute__((ext_vector_type(4))) float f32x4;      // MFMA C/D frag

// ---------------------------------------------------------------------------
// Storage-type adapters for xw (fp32 if workspace fits it, else bf16).
// ---------------------------------------------------------------------------
__device__ inline unsigned short f2bf_raw(float f) {
  __hip_bfloat16 b = __float2bfloat16(f);
  return *reinterpret_cast<unsigned short*>(&b);
}

template <typename XT> struct XConv;
template <> struct XConv<float> {
  typedef float4 Raw;
  static constexpr int CH = 2;   // burst regs: 2buf*2*4*4 = 64 VGPR
  static __device__ inline Raw loadraw(const float* p) {
    return *reinterpret_cast<const float4*>(p);
  }
  static __device__ inline float extract(const Raw& r, int i) {
    return reinterpret_cast<const float*>(&r)[i];
  }
  static __device__ inline void store4(float* p, float a, float b, float c, float d) {
    *reinterpret_cast<float4*>(p) = make_float4(a, b, c, d);
  }
};
template <> struct XConv<__hip_bfloat16> {
  typedef ushort4 Raw;
  static constexpr int CH = 4;   // burst regs: 2buf*4*4*2 = 64 VGPR
  static __device__ inline Raw loadraw(const __hip_bfloat16* p) {
    return *reinterpret_cast<const ushort4*>(p);
  }
  static __device__ inline float extract(const Raw& r, int i) {
    unsigned u = reinterpret_cast<const unsigned short*>(&r)[i];
    return __uint_as_float(u << 16);
  }
  static __device__ inline void store4(__hip_bfloat16* p, float a, float b, float c, float d) {
    ushort4 u = make_ushort4(f2bf_raw(a), f2bf_raw(b), f2bf_raw(c), f2bf_raw(d));
    *reinterpret_cast<ushort4*>(p) = u;
  }
};

// ---------------------------------------------------------------------------
// GEMM: xw[m][n] = sum_k x[m][k] * w_in[n][k];  M = B*T = 256000, K=128, N=256
// (unchanged -- keeps xw bit-identical to the passing rounds)
// ---------------------------------------------------------------------------
template <typename XT>
__global__ __launch_bounds__(256) void gemm_xw(const float* __restrict__ x,
                                               const float* __restrict__ w_in,
                                               XT* __restrict__ xw) {
  constexpr int K = 128;
  constexpr int SA = 68;
  __shared__ float As[K][SA];
  __shared__ float Bs[K][SA];

  const int m0 = blockIdx.x * 64;
  const int n0 = blockIdx.y * 64;
  const int tid = threadIdx.x;

  {
    const int r  = tid >> 2;
    const int cq = tid & 3;
    const float* xa = x    + (size_t)(m0 + r) * K;
    const float* xb = w_in + (size_t)(n0 + r) * K;
#pragma unroll
    for (int j = 0; j < 8; ++j) {
      const int c = (cq + (j << 2)) << 2;
      float4 av = *reinterpret_cast<const float4*>(xa + c);
      float4 bv = *reinterpret_cast<const float4*>(xb + c);
      As[c + 0][r] = av.x; As[c + 1][r] = av.y; As[c + 2][r] = av.z; As[c + 3][r] = av.w;
      Bs[c + 0][r] = bv.x; Bs[c + 1][r] = bv.y; Bs[c + 2][r] = bv.z; Bs[c + 3][r] = bv.w;
    }
  }
  __syncthreads();

  const int tn = (tid & 15) << 2;
  const int tm = (tid >> 4) << 2;
  float acc[4][4] = {};

#pragma unroll 16
  for (int k = 0; k < K; ++k) {
    float4 a = *reinterpret_cast<const float4*>(&As[k][tm]);
    float4 b = *reinterpret_cast<const float4*>(&Bs[k][tn]);
    acc[0][0] += a.x * b.x; acc[0][1] += a.x * b.y; acc[0][2] += a.x * b.z; acc[0][3] += a.x * b.w;
    acc[1][0] += a.y * b.x; acc[1][1] += a.y * b.y; acc[1][2] += a.y * b.z; acc[1][3] += a.y * b.w;
    acc[2][0] += a.z * b.x; acc[2][1] += a.z * b.y; acc[2][2] += a.z * b.z; acc[2][3] += a.z * b.w;
    acc[3][0] += a.w * b.x; acc[3][1] += a.w * b.y; acc[3][2] += a.w * b.z; acc[3][3] += a.w * b.w;
  }

#pragma unroll
  for (int im = 0; im < 4; ++im) {
    XT* p = xw + (size_t)(m0 + tm + im) * H + (n0 + tn);
    XConv<XT>::store4(p, acc[im][0], acc[im][1], acc[im][2], acc[im][3]);
  }
}

// ---------------------------------------------------------------------------
// LIF scan v7: dense MFMA recurrence + CHUNKED double-buffered xw prefetch.
//   Round-8 counters: ~2990 cy/step, of which ~1300 cy = waits. Cause: the
//   per-step xw reload is issued mid-step and __syncthreads drains vmcnt(0)
//   at EVERY barrier -> each step pays up to a full HBM latency.
//   Fix: burst-load CH steps of xw into a double-buffered register file
//   (BA/BB, 64 VGPR); the burst is issued right AFTER the first barrier of a
//   chunk, so it is ~1 full step old at the next barrier -> drain ~ 0, and
//   the remaining CH-1 barriers have zero outstanding VMEM.
//   Numerics are bit-identical to round 8 (absmax 0.0): exact-split W
//   (2 x f16: W*2^10 = hi + 2^-12*mid), same op order everywhere.
// ---------------------------------------------------------------------------

template <typename XT>
__global__ __launch_bounds__(256, 1) void scan_lif(const XT* __restrict__ xw,
                                                   const float* __restrict__ w_rec,
                                                   const float* __restrict__ fc_w,
                                                   const float* __restrict__ fc_b,
                                                   float* __restrict__ out) {
  constexpr int CH = XConv<XT>::CH;
  constexpr int NC = T / CH;           // 250 (bf16) / 500 (fp32), even

  const int tid = threadIdx.x;
  const int w  = tid >> 6;   // wave 0..3: W rows 64w..64w+63
  const int l  = tid & 63;
  const int lg = l & 15;     // A-row-in-tile / D-col (batch) / Z row
  const int lk = l >> 4;     // k-group / D row-group
  const int g0 = blockIdx.x * 16;

  // Z[g][k] as f16, row stride 264 shorts (528B, 16B-aligned rows).
  __shared__ unsigned short Zb[2][16][264];
  __shared__ float red[16][2];

  {
    unsigned* p = reinterpret_cast<unsigned*>(&Zb[0][0][0]);
    for (int i = tid; i < (int)(sizeof(Zb) / 4); i += 256) p[i] = 0u;
  }
  if (tid < 32) (&red[0][0])[tid] = 0.f;

  // ---- Load W into split f16 A-fragments, once. ----
  half8v afr_h[4][8], afr_m[4][8];
#pragma unroll
  for (int rt = 0; rt < 4; ++rt) {
    const float* wrow = w_rec + (size_t)(64 * w + 16 * rt + lg) * H + 8 * lk;
#pragma unroll
    for (int ks = 0; ks < 8; ++ks) {
      half8v fh, fm;
#pragma unroll
      for (int e = 0; e < 8; ++e) {
        const float ws = wrow[32 * ks + e] * 1024.f;   // exact (pow2)
        const _Float16 h = (_Float16)ws;               // RNE
        const float r = ws - (float)h;                 // exact in fp32
        fh[e] = h;
        fm[e] = (_Float16)(r * 4096.f);                // RNE, scaled to normal
      }
      afr_h[rt][ks] = fh;
      afr_m[rt][ks] = fm;
    }
  }

  // ---- LIF state: lane owns (h = 64w+16rt+4lk+r, g = g0+lg), i = rt*4+r ----
  float v[16], cur[16];
  int   cnt[16];
#pragma unroll
  for (int i = 0; i < 16; ++i) { v[i] = 0.f; cur[i] = 0.f; cnt[i] = 0; }

  // Incremental per-lane xw pointer: chunk c covers steps c*CH .. c*CH+CH-1.
  const XT* xcl = xw + (size_t)(g0 + lg) * T * H + 64 * w + 4 * lk;

  // Burst register file: double-buffered CH-step chunks (all static indexing).
  typename XConv<XT>::Raw BA[CH][4], BB[CH][4];

  // Load chunk 0 into BA; advances xcl by CH*H.
#define LOADCH(NB) do {                                                       \
    _Pragma("unroll")                                                         \
    for (int s_ = 0; s_ < CH; ++s_)                                           \
      _Pragma("unroll")                                                       \
      for (int rt_ = 0; rt_ < 4; ++rt_)                                       \
        NB[s_][rt_] = XConv<XT>::loadraw(xcl + s_ * H + 16 * rt_);            \
    xcl += CH * H;                                                            \
  } while (0)

  LOADCH(BA);
  __syncthreads();  // Z zero + red zero visible; drains the chunk-0 burst once

  // One LIF step: consume XR (= xw_t), read Z buf RD (= z_{t-1}), write z_t
  // into buf WR. Exactly one barrier. (Identical numerics to round 8.)
#define LSTEP(XR, RD, WR) do {                                                 \
    f32x4 ach[4], acm[4];                                                      \
    _Pragma("unroll")                                                          \
    for (int rt = 0; rt < 4; ++rt) {                                           \
      ach[rt] = (f32x4){0.f, 0.f, 0.f, 0.f};                                   \
      acm[rt] = (f32x4){0.f, 0.f, 0.f, 0.f};                                   \
    }                                                                          \
    _Pragma("unroll")                                                          \
    for (int ksg = 0; ksg < 2; ++ksg) {                                        \
      half8v bf[4];                                                            \
      _Pragma("unroll")                                                        \
      for (int k2 = 0; k2 < 4; ++k2)                                           \
        bf[k2] = *reinterpret_cast<const half8v*>(                             \
            &Zb[RD][lg][32 * (4 * ksg + k2) + 8 * lk]);                        \
      _Pragma("unroll")                                                        \
      for (int k2 = 0; k2 < 4; ++k2) {                                         \
        const int ks = 4 * ksg + k2;                                           \
        _Pragma("unroll")                                                      \
        for (int rt = 0; rt < 4; ++rt) {                                       \
          ach[rt] = __builtin_amdgcn_mfma_f32_16x16x32_f16(afr_h[rt][ks],      \
                        bf[k2], ach[rt], 0, 0, 0);                             \
          acm[rt] = __builtin_amdgcn_mfma_f32_16x16x32_f16(afr_m[rt][ks],      \
                        bf[k2], acm[rt], 0, 0, 0);                             \
        }                                                                      \
      }                                                                        \
    }                                                                          \
    _Pragma("unroll")                                                          \
    for (int rt = 0; rt < 4; ++rt) {                                           \
      ushort4 zw;                                                              \
      _Pragma("unroll")                                                        \
      for (int r = 0; r < 4; ++r) {                                            \
        const int i = rt * 4 + r;                                              \
        const float rec = (ach[rt][r] + acm[rt][r] * (1.f / 4096.f))           \
                          * (1.f / 1024.f);                                    \
        const float xt = XConv<XT>::extract(XR[rt], r);                        \
        const float vd = v[i] + DT_TAU_MEM * (cur[i] - v[i]);                  \
        const int z = vd > V_THRESH;                                           \
        v[i] = z ? 0.f : vd;                                                   \
        cur[i] = cur[i] * SYN_DECAY + xt + rec;                                \
        cnt[i] += z;                                                           \
        reinterpret_cast<unsigned short*>(&zw)[r] = z ? 0x3C00u : 0u;          \
      }                                                                        \
      *reinterpret_cast<ushort4*>(&Zb[WR][lg][64 * w + 16 * rt + 4 * lk]) = zw; \
    }                                                                          \
    __syncthreads();                                                           \
  } while (0)

  // Chunk: consume CB's CH steps; optionally burst-load NB for the next chunk
  // right after the FIRST step's barrier (so the loads are ~1 step old at the
  // next barrier -> vmcnt drain ~0, and later barriers see 0 outstanding).
#define CHUNKL(CB, NB) do {                                                   \
    LSTEP(CB[0], 0, 1);                                                       \
    LOADCH(NB);                                                               \
    LSTEP(CB[1], 1, 0);                                                       \
    if constexpr (CH == 4) {                                                  \
      LSTEP(CB[2], 0, 1);                                                     \
      LSTEP(CB[3], 1, 0);                                                     \
    }                                                                         \
  } while (0)

#define CHUNKN(CB) do {                                                       \
    LSTEP(CB[0], 0, 1);                                                       \
    LSTEP(CB[1], 1, 0);                                                       \
    if constexpr (CH == 4) {                                                  \
      LSTEP(CB[2], 0, 1);                                                     \
      LSTEP(CB[3], 1, 0);                                                     \
    }                                                                         \
  } while (0)

  for (int j = 0; j < NC / 2 - 1; ++j) {
    CHUNKL(BA, BB);   // consume chunk 2j,   load chunk 2j+1
    CHUNKL(BB, BA);   // consume chunk 2j+1, load chunk 2j+2
  }
  CHUNKL(BA, BB);     // consume chunk NC-2, load chunk NC-1
  CHUNKN(BB);         // consume chunk NC-1 (nothing left to load)

#undef CHUNKL
#undef CHUNKN
#undef LSTEP
#undef LOADCH

  // ---- Readout: out[g][o] = sum_h cnt[h,g] * fc_w[o][h] + fc_b[o] ----
  float po0 = 0.f, po1 = 0.f;
#pragma unroll
  for (int rt = 0; rt < 4; ++rt)
#pragma unroll
    for (int r = 0; r < 4; ++r) {
      const int h = 64 * w + 16 * rt + 4 * lk + r;
      const float c = (float)cnt[rt * 4 + r];
      po0 += c * fc_w[h];
      po1 += c * fc_w[H + h];
    }
  atomicAdd(&red[lg][0], po0);
  atomicAdd(&red[lg][1], po1);
  __syncthreads();
  if (tid < 32) {
    const int g = tid >> 1, o = tid & 1;
    out[(size_t)(g0 + g) * O + o] = red[g][o] + fc_b[o];
  }
}

// ---------------------------------------------------------------------------
extern "C" void kernel_launch(void* const* d_in, const int* in_sizes, int n_in,
                              void* d_out, int out_size, void* d_ws, size_t ws_size,
                              hipStream_t stream) {
  const float* x     = (const float*)d_in[0];
  const float* w_in  = (const float*)d_in[1];
  const float* w_rec = (const float*)d_in[2];
  const float* fc_w  = (const float*)d_in[3];
  const float* fc_b  = (const float*)d_in[4];
  float* out = (float*)d_out;

  // workspace: xw only (w_rec consumed in native layout by scan_lif)
  const size_t xw_elems = (size_t)B * T * H;
  const bool use_f32 = ws_size >= xw_elems * sizeof(float);

  if (use_f32) {
    float* xw = (float*)d_ws;
    gemm_xw<float><<<dim3(B * T / 64, H / 64), 256, 0, stream>>>(x, w_in, xw);
    scan_lif<float><<<B / 16, 256, 0, stream>>>(xw, w_rec, fc_w, fc_b, out);
  } else {
    __hip_bfloat16* xw = (__hip_bfloat16*)d_ws;
    gemm_xw<__hip_bfloat16><<<dim3(B * T / 64, H / 64), 256, 0, stream>>>(x, w_in, xw);
    scan_lif<__hip_bfloat16><<<B / 16, 256, 0, stream>>>(xw, w_rec, fc_w, fc_b, out);
  }
}